// Round 1
// 814.034 us; speedup vs baseline: 1.2093x; 1.2093x over previous
//
#include <hip/hip_runtime.h>
#include <hip/hip_bf16.h>

#define EMB 64

__device__ __forceinline__ float bf2f(unsigned short h) {
    return __uint_as_float(((unsigned)h) << 16);
}
__device__ __forceinline__ unsigned short f2bf(float f) {
    unsigned u = __float_as_uint(f);
    unsigned r = (u + 0x7fffu + ((u >> 16) & 1u)) >> 16;  // RNE
    return (unsigned short)r;
}

// ---- user row_ptr via binary search over sorted first half of row ----
__global__ void urp_kernel(const int* __restrict__ row, int* __restrict__ urp, int NU, int Eh) {
    int r = blockIdx.x * blockDim.x + threadIdx.x;
    if (r > NU) return;
    if (r == NU) { urp[NU] = Eh; return; }
    int lo = 0, hi = Eh;
    while (lo < hi) {
        int mid = (lo + hi) >> 1;
        if (row[mid] < r) lo = mid + 1; else hi = mid;
    }
    urp[r] = lo;
}

// ---- item degree histogram over first-half cols (item ids) ----
__global__ void ideg_kernel(const int* __restrict__ colh, int* __restrict__ degit, int Eh, int NU) {
    int e = blockIdx.x * blockDim.x + threadIdx.x;
    if (e < Eh) atomicAdd(&degit[colh[e] - NU], 1);
}

// ---- dinv = rsqrt(deg + 1) for all N nodes ----
__global__ void dinv_kernel(const int* __restrict__ urp, const int* __restrict__ degit,
                            float* __restrict__ dinv, int NU, int N) {
    int i = blockIdx.x * blockDim.x + threadIdx.x;
    if (i >= N) return;
    int d = (i < NU) ? (urp[i + 1] - urp[i]) : degit[i - NU];
    dinv[i] = rsqrtf((float)d + 1.0f);
}

// ---- exclusive scan over item degrees ----
__global__ void scan1_kernel(const int* __restrict__ deg, int* __restrict__ excl,
                             int* __restrict__ partials, int N) {
    __shared__ int sh[256];
    int b = blockIdx.x, t = threadIdx.x;
    int base = b * 1024 + t * 4;
    int d0 = (base + 0 < N) ? deg[base + 0] : 0;
    int d1 = (base + 1 < N) ? deg[base + 1] : 0;
    int d2 = (base + 2 < N) ? deg[base + 2] : 0;
    int d3 = (base + 3 < N) ? deg[base + 3] : 0;
    int tsum = d0 + d1 + d2 + d3;
    sh[t] = tsum;
    __syncthreads();
    for (int off = 1; off < 256; off <<= 1) {
        int v = (t >= off) ? sh[t - off] : 0;
        __syncthreads();
        sh[t] += v;
        __syncthreads();
    }
    int excl_t = sh[t] - tsum;
    if (base + 0 < N) excl[base + 0] = excl_t;
    if (base + 1 < N) excl[base + 1] = excl_t + d0;
    if (base + 2 < N) excl[base + 2] = excl_t + d0 + d1;
    if (base + 3 < N) excl[base + 3] = excl_t + d0 + d1 + d2;
    if (t == 255) partials[b] = sh[t];
}

__global__ void scan2_kernel(int* __restrict__ partials, int nb) {
    __shared__ int sh[512];
    int t = threadIdx.x;
    int v = (t < nb) ? partials[t] : 0;
    sh[t] = v;
    __syncthreads();
    for (int off = 1; off < 512; off <<= 1) {
        int u = (t >= off) ? sh[t - off] : 0;
        __syncthreads();
        sh[t] += u;
        __syncthreads();
    }
    if (t < nb) partials[t] = sh[t] - v;  // exclusive
}

__global__ void scan3_kernel(const int* __restrict__ excl, const int* __restrict__ partials,
                             int* __restrict__ irp, int* __restrict__ cursor, int N, int E) {
    int i = blockIdx.x * blockDim.x + threadIdx.x;
    if (i < N) {
        int v = excl[i] + partials[i >> 10];
        irp[i] = v;
        cursor[i] = v;
    }
    if (i == N) irp[N] = E;
}

// ---- item CSR fill: scatter user ids into per-item segments ----
__global__ void ifill_kernel(const int* __restrict__ rowh, const int* __restrict__ colh,
                             int* __restrict__ cursor, int* __restrict__ icols, int Eh, int NU) {
    int e = blockIdx.x * blockDim.x + threadIdx.x;
    if (e < Eh) {
        int u = rowh[e];
        int itl = colh[e] - NU;
        int pos = atomicAdd(&cursor[itl], 1);
        icols[pos] = u;
    }
}

// ---- x0 = bf16(concat(user_emb, item_emb)), vectorized float4 -> ushort4 ----
__global__ void init_kernel(const float* __restrict__ u, const float* __restrict__ it,
                            unsigned short* __restrict__ x, long nu_elems, long total) {
    long j4 = ((long)blockIdx.x * blockDim.x + threadIdx.x) * 4;
    if (j4 >= total) return;
    // EMB=64 -> nu_elems and total are multiples of 4; no straddle possible
    float4 v = (j4 < nu_elems) ? ((const float4*)u)[j4 >> 2]
                               : ((const float4*)it)[(j4 - nu_elems) >> 2];
    ushort4 o;
    o.x = f2bf(v.x); o.y = f2bf(v.y); o.z = f2bf(v.z); o.w = f2bf(v.w);
    ((ushort4*)x)[j4 >> 2] = o;
}

// ---- fused gather SpMM over bf16 x: one 16-LANE GROUP per node, 4 edges/iter ----
// acc = dinv[i]^2*xc[i,:] + sum_k dinv[i]*dinv[c_k]*xc[c_k,:]
// if xn: xn = bf16(acc); else (final layer): out = f32(x0)+f32(x1)+f32(xc)+acc
// 4 nodes per wave (consecutive ids) -> no cross-lane reduce, full-width
// coalesced epilogue (4 rows = 512B bf16 / 1KB f32 per wave).
__global__ void spmm_kernel(const int* __restrict__ urp, const int* __restrict__ irp,
                            const int* __restrict__ colg, const int* __restrict__ icols,
                            const float* __restrict__ dinv,
                            const unsigned short* __restrict__ xc,
                            unsigned short* __restrict__ xn,
                            const unsigned short* __restrict__ x0b,
                            const unsigned short* __restrict__ x1b,
                            float* __restrict__ out, int NU, int N) {
    long t = (long)blockIdx.x * blockDim.x + threadIdx.x;
    int i = (int)(t >> 4);   // node id: one 16-lane group per node
    if (i >= N) return;
    int q = (int)(t & 15);   // ushort4 slot within the 64-elem row

    const int* list;
    int s, e;
    if (i < NU) { s = urp[i]; e = urp[i + 1]; list = colg; }
    else        { int j = i - NU; s = irp[j]; e = irp[j + 1]; list = icols; }
    float di = dinv[i];
    const ushort4* __restrict__ xc4 = (const ushort4*)xc;

    // self-row load (independent; hoisted above the edge loop)
    long p = (long)i * 16 + q;
    ushort4 sv = xc4[p];

    float ax = 0.f, ay = 0.f, az = 0.f, aw = 0.f;
    for (int k0 = s; k0 < e; k0 += 4) {
        int   c[4];
        float w[4];
#pragma unroll
        for (int j = 0; j < 4; ++j) {
            int k = k0 + j;
            bool v = (k < e);
            c[j] = v ? list[k] : 0;
            w[j] = v ? di * dinv[c[j]] : 0.0f;
        }
#pragma unroll
        for (int j = 0; j < 4; ++j) {
            ushort4 u = xc4[(long)c[j] * 16 + q];
            ax += w[j] * bf2f(u.x);
            ay += w[j] * bf2f(u.y);
            az += w[j] * bf2f(u.z);
            aw += w[j] * bf2f(u.w);
        }
    }

    // self-loop term; no cross-lane reduction needed (group owns the whole row)
    float sw = di * di;
    ax += sw * bf2f(sv.x);
    ay += sw * bf2f(sv.y);
    az += sw * bf2f(sv.z);
    aw += sw * bf2f(sv.w);

    if (xn) {
        ushort4 o;
        o.x = f2bf(ax); o.y = f2bf(ay); o.z = f2bf(az); o.w = f2bf(aw);
        ((ushort4*)xn)[p] = o;
    } else {
        ushort4 a0 = ((const ushort4*)x0b)[p];
        ushort4 a1 = ((const ushort4*)x1b)[p];
        float4 o;
        o.x = bf2f(a0.x) + bf2f(a1.x) + bf2f(sv.x) + ax;
        o.y = bf2f(a0.y) + bf2f(a1.y) + bf2f(sv.y) + ay;
        o.z = bf2f(a0.z) + bf2f(a1.z) + bf2f(sv.z) + az;
        o.w = bf2f(a0.w) + bf2f(a1.w) + bf2f(sv.w) + aw;
        ((float4*)out)[p] = o;
    }
}

extern "C" void kernel_launch(void* const* d_in, const int* in_sizes, int n_in,
                              void* d_out, int out_size, void* d_ws, size_t ws_size,
                              hipStream_t stream) {
    const int*   edge_index = (const int*)d_in[0];   // [2, E]
    const float* user_emb   = (const float*)d_in[1]; // [NU, 64]
    const float* item_emb   = (const float*)d_in[2]; // [NI, 64]
    float* out = (float*)d_out;

    const int  E  = in_sizes[0] / 2;
    const int  Eh = E / 2;             // first half: user rows (sorted), cols = items
    const int  NU = in_sizes[1] / EMB;
    const int  NI = in_sizes[2] / EMB;
    const int  N  = NU + NI;
    const long total = (long)N * EMB;

    const int* row = edge_index;       // [E]
    const int* col = edge_index + E;   // [E]
    const int* rowh = row;             // first Eh: sorted user ids
    const int* colh = col;             // first Eh: item ids (random)

    // workspace layout:
    // urp[NU+1] | degit[NI] | excl[NI] | partials[512] | irp[NI+1] | cursor[NI] |
    // icols[Eh] | dinv[N] f | x0[total] bf16 | x1[total] bf16 | x2[total] bf16
    int*   urp      = (int*)d_ws;
    int*   degit    = urp + (NU + 1);
    int*   excl     = degit + NI;
    int*   partials = excl + NI;
    int*   irp      = partials + 512;
    int*   cursor   = irp + (NI + 1);
    int*   icols    = cursor + NI;
    float* dinv     = (float*)(icols + Eh);
    unsigned short* x0 = (unsigned short*)(dinv + N);
    x0 = (unsigned short*)(((uintptr_t)x0 + 15) & ~(uintptr_t)15);
    unsigned short* x1 = x0 + total;
    unsigned short* x2 = x1 + total;

    hipMemsetAsync(degit, 0, (size_t)NI * sizeof(int), stream);

    urp_kernel<<<(NU + 256) / 256, 256, 0, stream>>>(row, urp, NU, Eh);
    ideg_kernel<<<(Eh + 255) / 256, 256, 0, stream>>>(colh, degit, Eh, NU);
    dinv_kernel<<<(N + 255) / 256, 256, 0, stream>>>(urp, degit, dinv, NU, N);

    int nb = (NI + 1023) / 1024;  // <= 512
    scan1_kernel<<<nb, 256, 0, stream>>>(degit, excl, partials, NI);
    scan2_kernel<<<1, 512, 0, stream>>>(partials, nb);
    scan3_kernel<<<(NI + 1 + 255) / 256, 256, 0, stream>>>(excl, partials, irp, cursor, NI, Eh);

    ifill_kernel<<<(Eh + 255) / 256, 256, 0, stream>>>(rowh, colh, cursor, icols, Eh, NU);

    init_kernel<<<(int)((total / 4 + 255) / 256), 256, 0, stream>>>(user_emb, item_emb, x0,
                                                                    (long)NU * EMB, total);

    // one 16-lane group per node -> 16 nodes per 256-thread block
    int blocks = (N + 15) / 16;
    // L0: x1 = A(x0)
    spmm_kernel<<<blocks, 256, 0, stream>>>(urp, irp, col, icols, dinv, x0, x1,
                                            nullptr, nullptr, nullptr, NU, N);
    // L1: x2 = A(x1)
    spmm_kernel<<<blocks, 256, 0, stream>>>(urp, irp, col, icols, dinv, x1, x2,
                                            nullptr, nullptr, nullptr, NU, N);
    // L2 (fused final): out = x0 + x1 + x2 + A(x2)
    spmm_kernel<<<blocks, 256, 0, stream>>>(urp, irp, col, icols, dinv, x2, nullptr,
                                            x0, x1, out, NU, N);
}